// Round 2
// baseline (8463.312 us; speedup 1.0000x reference)
//
#include <hip/hip_runtime.h>

// Problem: N=64 batch, T=512 steps, D=H=512.
//   xw = x @ Wx + b          (32768x512 @ 512x512)  -> written into d_out
//   h_t = tanh(h_{t-1} @ Wh + xw_t)                 -> overwrites d_out in place
//
// Design:
//  - prepack: Wx, Wh fp32 -> bf16 MFMA B-fragment layout in ws (one-time, tiny)
//  - gemm_xw: bf16 MFMA GEMM, A = x converted inline, out fp32 into d_out
//  - rnn_scan: persistent kernel, 8 blocks (4 groups x 2 column-halves).
//      Each block: 1024 thr = 16 waves, wave owns 16 cols of Wh in 64 VGPRs
//      (16 bf16 B-frags). Group owns 16 batch rows (= MFMA M dim).
//      Per step: poll peer seq-flag, load h_{t-1} bf16 frags from ping-pong
//      exchange buf, 16 MFMA, tanh epilogue, write h to d_out + exchange buf,
//      fence + barrier + release seq-flag.

typedef __attribute__((ext_vector_type(8))) short short8;
typedef __attribute__((ext_vector_type(4))) float f32x4;

#define DIM 512
#define T_S 512
#define N_B 64

union Frag {
  uint4 v;
  short8 s;
  unsigned short u[8];
};

static __device__ __forceinline__ unsigned short f2bf(float f) {
  // round-to-nearest-even fp32 -> bf16
  union { float f; unsigned u; } v;
  v.f = f;
  unsigned r = v.u + 0x7FFFu + ((v.u >> 16) & 1u);
  return (unsigned short)(r >> 16);
}

static __device__ __forceinline__ float fast_tanh(float s) {
  // tanh(s) = 1 - 2/(exp(2s)+1);  exp(2s) = 2^(s * 2*log2(e))
  float e = __builtin_amdgcn_exp2f(2.885390082f * s);
  return 1.0f - 2.0f * __builtin_amdgcn_rcpf(e + 1.0f);
}

// ---------------------------------------------------------------------------
// Pack W (512x512 fp32, k-major rows) into bf16 MFMA B-fragments.
// Frag (kk, cc): lane l holds B[k = 32*kk + 8*(l>>4) + j][col = 16*cc + (l&15)],
// j = 0..7, stored as uint4 at dst[(kk*32+cc)*64 + lane].
// grid: 1024 blocks x 64 thr  (bid>>9: 0 = Wx, 1 = Wh)
// ---------------------------------------------------------------------------
__global__ __launch_bounds__(64) void prepack(const float* __restrict__ Wx,
                                              const float* __restrict__ Wh,
                                              uint4* __restrict__ wxb,
                                              uint4* __restrict__ whb) {
  int bid = blockIdx.x;
  int mat = bid >> 9;
  int idx = bid & 511;
  int kk = idx >> 5, cc = idx & 31;
  int lane = threadIdx.x;
  int lo = lane & 15, hi = lane >> 4;
  const float* src = mat ? Wh : Wx;
  uint4* dst = mat ? whb : wxb;
  int col = cc * 16 + lo;
  int kbase = kk * 32 + hi * 8;
  Frag fr;
#pragma unroll
  for (int j = 0; j < 8; ++j)
    fr.u[j] = f2bf(src[(size_t)(kbase + j) * DIM + col]);
  dst[(kk * 32 + cc) * 64 + lane] = fr.v;
}

// ---------------------------------------------------------------------------
// xw = x @ Wx + b  -> out (fp32).  M = 32768, K = N = 512.
// Block 256 thr = 4 waves; block tile 64(M) x 128(N); wave tile 64 x 32.
// grid 2048: bid = m*4 + nb  (same-m blocks adjacent -> L2 reuse of x)
// ---------------------------------------------------------------------------
__global__ __launch_bounds__(256) void gemm_xw(const float* __restrict__ x,
                                               const uint4* __restrict__ wxb,
                                               const float* __restrict__ bias,
                                               float* __restrict__ out) {
  int bid = blockIdx.x;
  int m = bid >> 2, nb = bid & 3;
  int wave = threadIdx.x >> 6, lane = threadIdx.x & 63;
  int lo = lane & 15, hi = lane >> 4;
  int rowbase = m * 64;
  int colbase = nb * 128 + wave * 32;

  f32x4 acc[4][2];
#pragma unroll
  for (int mi = 0; mi < 4; ++mi)
#pragma unroll
    for (int ni = 0; ni < 2; ++ni) acc[mi][ni] = (f32x4){0.f, 0.f, 0.f, 0.f};

  for (int kk = 0; kk < 16; ++kk) {
    short8 afrag[4];
#pragma unroll
    for (int mi = 0; mi < 4; ++mi) {
      const float* ap = x + (size_t)(rowbase + mi * 16 + lo) * DIM + kk * 32 + hi * 8;
      float4 f0 = *(const float4*)ap;
      float4 f1 = *(const float4*)(ap + 4);
      Frag a;
      a.u[0] = f2bf(f0.x); a.u[1] = f2bf(f0.y); a.u[2] = f2bf(f0.z); a.u[3] = f2bf(f0.w);
      a.u[4] = f2bf(f1.x); a.u[5] = f2bf(f1.y); a.u[6] = f2bf(f1.z); a.u[7] = f2bf(f1.w);
      afrag[mi] = a.s;
    }
#pragma unroll
    for (int ni = 0; ni < 2; ++ni) {
      int cc = nb * 8 + wave * 2 + ni;
      Frag b;
      b.v = wxb[(kk * 32 + cc) * 64 + lane];
#pragma unroll
      for (int mi = 0; mi < 4; ++mi)
        acc[mi][ni] = __builtin_amdgcn_mfma_f32_16x16x32_bf16(afrag[mi], b.s, acc[mi][ni], 0, 0, 0);
    }
  }
#pragma unroll
  for (int ni = 0; ni < 2; ++ni) {
    int col = colbase + ni * 16 + lo;
    float bv = bias[col];
#pragma unroll
    for (int mi = 0; mi < 4; ++mi)
#pragma unroll
      for (int r = 0; r < 4; ++r) {
        int row = rowbase + mi * 16 + hi * 4 + r;
        out[(size_t)row * DIM + col] = acc[mi][ni][r] + bv;
      }
  }
}

// ---------------------------------------------------------------------------
// Persistent recurrent scan. grid = 8 blocks x 1024 thr.
//   group g = blockIdx>>1 owns batch rows [16g, 16g+16); half = blockIdx&1
//   owns columns [256*half, 256*half+256); wave owns 16 of those columns.
// hx: bf16 ping-pong h exchange [2][64][512]; seq: per-block step flags [8].
// out holds xw on entry (per (n,t,col)); overwritten with h in place.
// ---------------------------------------------------------------------------
__global__ __launch_bounds__(1024) void rnn_scan(const float* __restrict__ h0,
                                                 const uint4* __restrict__ whb,
                                                 float* __restrict__ out,
                                                 unsigned short* __restrict__ hx,
                                                 unsigned int* __restrict__ seq) {
  int g = blockIdx.x >> 1, half = blockIdx.x & 1;
  int wave = threadIdx.x >> 6, lane = threadIdx.x & 63;
  int lo = lane & 15, hi = lane >> 4;
  int c0 = half * 256 + wave * 16;
  int cc = c0 >> 4;

  // resident Wh column slice: 16 B-frags = 64 VGPRs
  uint4 bw[16];
#pragma unroll
  for (int kk = 0; kk < 16; ++kk) bw[kk] = whb[(kk * 32 + cc) * 64 + lane];

  int nA = g * 16 + lo;  // batch row this lane supplies to the A operand
  const unsigned int* peer = seq + (g * 2 + (half ^ 1));
  unsigned int* self = seq + (g * 2 + half);

  for (int t = 0; t < T_S; ++t) {
    f32x4 acc = (f32x4){0.f, 0.f, 0.f, 0.f};

    if (t == 0) {
      const float* hp = h0 + (size_t)nA * DIM + hi * 8;
#pragma unroll
      for (int kk = 0; kk < 16; ++kk) {
        float4 f0 = *(const float4*)(hp + kk * 32);
        float4 f1 = *(const float4*)(hp + kk * 32 + 4);
        Frag a;
        a.u[0] = f2bf(f0.x); a.u[1] = f2bf(f0.y); a.u[2] = f2bf(f0.z); a.u[3] = f2bf(f0.w);
        a.u[4] = f2bf(f1.x); a.u[5] = f2bf(f1.y); a.u[6] = f2bf(f1.z); a.u[7] = f2bf(f1.w);
        Frag b; b.v = bw[kk];
        acc = __builtin_amdgcn_mfma_f32_16x16x32_bf16(a.s, b.s, acc, 0, 0, 0);
      }
    } else {
      // wait for peer block's step t-1 (own block synced via barrier below)
      while (__hip_atomic_load(peer, __ATOMIC_ACQUIRE, __HIP_MEMORY_SCOPE_AGENT) < (unsigned)t)
        __builtin_amdgcn_s_sleep(1);

      const unsigned short* hb =
          hx + (size_t)((t - 1) & 1) * (N_B * DIM) + (size_t)nA * DIM + hi * 8;
      // two batches of 8 to bound register pressure (~120 VGPR total)
      uint4 a[8];
#pragma unroll
      for (int kk = 0; kk < 8; ++kk) a[kk] = *(const uint4*)(hb + kk * 32);
#pragma unroll
      for (int kk = 0; kk < 8; ++kk) {
        Frag af; af.v = a[kk];
        Frag bf; bf.v = bw[kk];
        acc = __builtin_amdgcn_mfma_f32_16x16x32_bf16(af.s, bf.s, acc, 0, 0, 0);
      }
#pragma unroll
      for (int kk = 0; kk < 8; ++kk) a[kk] = *(const uint4*)(hb + (kk + 8) * 32);
#pragma unroll
      for (int kk = 0; kk < 8; ++kk) {
        Frag af; af.v = a[kk];
        Frag bf; bf.v = bw[kk + 8];
        acc = __builtin_amdgcn_mfma_f32_16x16x32_bf16(af.s, bf.s, acc, 0, 0, 0);
      }
    }

    // epilogue: D row = 4*hi + r, col = lo  ->  n = 16g + 4*hi + r
    unsigned short* hw = hx + (size_t)(t & 1) * (N_B * DIM);
#pragma unroll
    for (int r = 0; r < 4; ++r) {
      int nr = g * 16 + hi * 4 + r;
      size_t oidx = ((size_t)nr * T_S + t) * DIM + c0 + lo;
      float s = acc[r] + out[oidx];  // + xw
      float h = fast_tanh(s);
      out[oidx] = h;
      hw[(size_t)nr * DIM + c0 + lo] = f2bf(h);
    }

    __threadfence();   // make h writes visible device-scope
    __syncthreads();   // whole block done with step t
    if (threadIdx.x == 0)
      __hip_atomic_store(self, (unsigned)(t + 1), __ATOMIC_RELEASE, __HIP_MEMORY_SCOPE_AGENT);
  }
}

// ---------------------------------------------------------------------------
extern "C" void kernel_launch(void* const* d_in, const int* in_sizes, int n_in,
                              void* d_out, int out_size, void* d_ws, size_t ws_size,
                              hipStream_t stream) {
  const float* x  = (const float*)d_in[0];
  const float* h0 = (const float*)d_in[1];
  const float* Wx = (const float*)d_in[2];
  const float* Wh = (const float*)d_in[3];
  const float* b  = (const float*)d_in[4];
  float* out = (float*)d_out;

  char* ws = (char*)d_ws;
  // ws layout: [0,64K) seq flags (+pad), [64K, 64K+512K) whb,
  //            [+512K) wxb, [+512K) hx ping-pong (128K). Total ~1.2 MB.
  unsigned int* seq = (unsigned int*)ws;
  uint4* whb = (uint4*)(ws + 65536);
  uint4* wxb = (uint4*)(ws + 65536 + 524288);
  unsigned short* hx = (unsigned short*)(ws + 65536 + 2 * 524288);

  // zero the seq flags each call (ws is poisoned once, never re-poisoned)
  (void)hipMemsetAsync(seq, 0, 65536, stream);

  prepack<<<1024, 64, 0, stream>>>(Wx, Wh, wxb, whb);
  gemm_xw<<<2048, 256, 0, stream>>>(x, wxb, b, out);
  rnn_scan<<<8, 1024, 0, stream>>>(h0, whb, out, hx, seq);
}

// Round 3
// 3235.578 us; speedup vs baseline: 2.6157x; 2.6157x over previous
//
#include <hip/hip_runtime.h>

// N=64, T=512, D=H=512.
//   xw = x @ Wx + b   -> d_out (fp32), big MFMA GEMM
//   h_t = tanh(h_{t-1} @ Wh + xw_t) -> overwrites d_out in place
//
// rnn_scan v2: NO cross-block communication (round-2 lesson: agent-scope
// acquire/release costs ~16 us/step in L2 wb/inv on multi-XCD gfx950).
// 4 blocks x 16 batch rows; each block owns ALL 512 columns:
//   - h in LDS (16x512 bf16, XOR-swizzled rows: byte ^= (row&7)<<4)
//   - Wh split: 128 VGPR/wave (kk 0..7) + 96 KB LDS (kk 8..10)
//     + streamed from L2 each step (kk 11..15), 2-deep pipelined.
//   - per step: 64 MFMA/wave (16 kk x 4 col-tiles), 2 barriers.

typedef __attribute__((ext_vector_type(8))) short short8;
typedef __attribute__((ext_vector_type(4))) float f32x4;

#define DIM 512
#define T_S 512

union Frag {
  uint4 v;
  short8 s;
  unsigned short u[8];
};

static __device__ __forceinline__ unsigned short f2bf(float f) {
  union { float f; unsigned u; } v;
  v.f = f;
  unsigned r = v.u + 0x7FFFu + ((v.u >> 16) & 1u);
  return (unsigned short)(r >> 16);
}

static __device__ __forceinline__ float fast_tanh(float s) {
  float e = __builtin_amdgcn_exp2f(2.885390082f * s);
  return 1.0f - 2.0f * __builtin_amdgcn_rcpf(e + 1.0f);
}

// ---------------------------------------------------------------------------
// Pack W (512x512 fp32) into bf16 MFMA B-fragments.
// Frag (kk, cc): lane l holds B[k=32kk+8(l>>4)+j][col=16cc+(l&15)], j=0..7,
// at dst[(kk*32+cc)*64 + lane].
// ---------------------------------------------------------------------------
__global__ __launch_bounds__(64) void prepack(const float* __restrict__ Wx,
                                              const float* __restrict__ Wh,
                                              uint4* __restrict__ wxb,
                                              uint4* __restrict__ whb) {
  int bid = blockIdx.x;
  int mat = bid >> 9;
  int idx = bid & 511;
  int kk = idx >> 5, cc = idx & 31;
  int lane = threadIdx.x;
  int lo = lane & 15, hi = lane >> 4;
  const float* src = mat ? Wh : Wx;
  uint4* dst = mat ? whb : wxb;
  int col = cc * 16 + lo;
  int kbase = kk * 32 + hi * 8;
  Frag fr;
#pragma unroll
  for (int j = 0; j < 8; ++j)
    fr.u[j] = f2bf(src[(size_t)(kbase + j) * DIM + col]);
  dst[(kk * 32 + cc) * 64 + lane] = fr.v;
}

// ---------------------------------------------------------------------------
// xw = x @ Wx + b -> out (fp32). M=32768, K=N=512. Unchanged from round 2.
// ---------------------------------------------------------------------------
__global__ __launch_bounds__(256) void gemm_xw(const float* __restrict__ x,
                                               const uint4* __restrict__ wxb,
                                               const float* __restrict__ bias,
                                               float* __restrict__ out) {
  int bid = blockIdx.x;
  int m = bid >> 2, nb = bid & 3;
  int wave = threadIdx.x >> 6, lane = threadIdx.x & 63;
  int lo = lane & 15, hi = lane >> 4;
  int rowbase = m * 64;
  int colbase = nb * 128 + wave * 32;

  f32x4 acc[4][2];
#pragma unroll
  for (int mi = 0; mi < 4; ++mi)
#pragma unroll
    for (int ni = 0; ni < 2; ++ni) acc[mi][ni] = (f32x4){0.f, 0.f, 0.f, 0.f};

  for (int kk = 0; kk < 16; ++kk) {
    short8 afrag[4];
#pragma unroll
    for (int mi = 0; mi < 4; ++mi) {
      const float* ap = x + (size_t)(rowbase + mi * 16 + lo) * DIM + kk * 32 + hi * 8;
      float4 f0 = *(const float4*)ap;
      float4 f1 = *(const float4*)(ap + 4);
      Frag a;
      a.u[0] = f2bf(f0.x); a.u[1] = f2bf(f0.y); a.u[2] = f2bf(f0.z); a.u[3] = f2bf(f0.w);
      a.u[4] = f2bf(f1.x); a.u[5] = f2bf(f1.y); a.u[6] = f2bf(f1.z); a.u[7] = f2bf(f1.w);
      afrag[mi] = a.s;
    }
#pragma unroll
    for (int ni = 0; ni < 2; ++ni) {
      int cc = nb * 8 + wave * 2 + ni;
      Frag b;
      b.v = wxb[(kk * 32 + cc) * 64 + lane];
#pragma unroll
      for (int mi = 0; mi < 4; ++mi)
        acc[mi][ni] = __builtin_amdgcn_mfma_f32_16x16x32_bf16(afrag[mi], b.s, acc[mi][ni], 0, 0, 0);
    }
  }
#pragma unroll
  for (int ni = 0; ni < 2; ++ni) {
    int col = colbase + ni * 16 + lo;
    float bv = bias[col];
#pragma unroll
    for (int mi = 0; mi < 4; ++mi)
#pragma unroll
      for (int r = 0; r < 4; ++r) {
        int row = rowbase + mi * 16 + hi * 4 + r;
        out[(size_t)row * DIM + col] = acc[mi][ni][r] + bv;
      }
  }
}

// ---------------------------------------------------------------------------
// Recurrent scan v2. grid = 4 blocks x 512 thr (8 waves).
// Block g owns batch rows [16g, 16g+16), all 512 columns.
// Wave w owns col-tiles cc = 4w..4w+3 (cols [64w, 64w+64)).
// ---------------------------------------------------------------------------
__shared__ uint4 wlds[8][3][4][64];            // 96 KB: Wh kk=8..10
__shared__ unsigned short hbuf[16 * 512];      // 16 KB: h, XOR-swizzled

static __device__ __forceinline__ uint4 ld_h(int lo, int kk, int hi) {
  // A-frag: row=lo, k0 = kk*32 + hi*8 -> 16 bytes, swizzled by row
  int byte = lo * 1024 + ((kk * 64 + hi * 16) ^ ((lo & 7) << 4));
  return *(const uint4*)((const char*)hbuf + byte);
}

static __device__ __forceinline__ void st_h(int row, int col, unsigned short v) {
  int byte = row * 1024 + ((col * 2) ^ ((row & 7) << 4));
  *(unsigned short*)((char*)hbuf + byte) = v;
}

__global__ __launch_bounds__(512) void rnn_scan(const float* __restrict__ h0,
                                                const uint4* __restrict__ whb,
                                                float* __restrict__ out) {
  int g = blockIdx.x;
  int w = threadIdx.x >> 6, lane = threadIdx.x & 63;
  int lo = lane & 15, hi = lane >> 4;

  // resident Wh: kk 0..7 for this wave's 4 col-tiles -> 32 uint4 = 128 VGPRs
  uint4 bw[8][4];
#pragma unroll
  for (int kk = 0; kk < 8; ++kk)
#pragma unroll
    for (int i = 0; i < 4; ++i)
      bw[kk][i] = whb[(kk * 32 + (w * 4 + i)) * 64 + lane];

  // LDS-resident Wh: kk 8..10
#pragma unroll
  for (int s = 0; s < 3; ++s)
#pragma unroll
    for (int i = 0; i < 4; ++i)
      wlds[w][s][i][lane] = whb[((8 + s) * 32 + (w * 4 + i)) * 64 + lane];

  // init h_0 into LDS (bf16, swizzled)
#pragma unroll
  for (int r = 0; r < 4; ++r)
#pragma unroll
    for (int i = 0; i < 4; ++i) {
      int row = hi * 4 + r;
      int col = w * 64 + i * 16 + lo;
      st_h(row, col, f2bf(h0[(size_t)(g * 16 + row) * DIM + col]));
    }
  __syncthreads();

#pragma unroll 1
  for (int t = 0; t < T_S; ++t) {
    // prefetch xw for this step (epilogue use; HBM latency hides under MFMA)
    float xwv[16];
#pragma unroll
    for (int r = 0; r < 4; ++r)
#pragma unroll
      for (int i = 0; i < 4; ++i)
        xwv[r * 4 + i] =
            out[((size_t)(g * 16 + hi * 4 + r) * T_S + t) * DIM + w * 64 + i * 16 + lo];

    // 2-deep pipeline for streamed Wh (kk 11..15)
    uint4 sw[2][4];
#pragma unroll
    for (int i = 0; i < 4; ++i) sw[0][i] = whb[(11 * 32 + (w * 4 + i)) * 64 + lane];
#pragma unroll
    for (int i = 0; i < 4; ++i) sw[1][i] = whb[(12 * 32 + (w * 4 + i)) * 64 + lane];

    f32x4 acc[4];
#pragma unroll
    for (int i = 0; i < 4; ++i) acc[i] = (f32x4){0.f, 0.f, 0.f, 0.f};

    // kk 0..7: register-resident weights
#pragma unroll
    for (int kk = 0; kk < 8; ++kk) {
      Frag a; a.v = ld_h(lo, kk, hi);
#pragma unroll
      for (int i = 0; i < 4; ++i) {
        Frag b; b.v = bw[kk][i];
        acc[i] = __builtin_amdgcn_mfma_f32_16x16x32_bf16(a.s, b.s, acc[i], 0, 0, 0);
      }
    }
    // kk 8..10: LDS-resident weights
#pragma unroll
    for (int s = 0; s < 3; ++s) {
      Frag a; a.v = ld_h(lo, 8 + s, hi);
#pragma unroll
      for (int i = 0; i < 4; ++i) {
        Frag b; b.v = wlds[w][s][i][lane];
        acc[i] = __builtin_amdgcn_mfma_f32_16x16x32_bf16(a.s, b.s, acc[i], 0, 0, 0);
      }
    }
    // kk 11..15: streamed from L2, 2-deep
#pragma unroll
    for (int s = 0; s < 5; ++s) {
      Frag a; a.v = ld_h(lo, 11 + s, hi);
      uint4 cur[4];
#pragma unroll
      for (int i = 0; i < 4; ++i) cur[i] = sw[s & 1][i];
      if (s + 2 < 5) {
#pragma unroll
        for (int i = 0; i < 4; ++i)
          sw[s & 1][i] = whb[((13 + s) * 32 + (w * 4 + i)) * 64 + lane];
      }
#pragma unroll
      for (int i = 0; i < 4; ++i) {
        Frag b; b.v = cur[i];
        acc[i] = __builtin_amdgcn_mfma_f32_16x16x32_bf16(a.s, b.s, acc[i], 0, 0, 0);
      }
    }

    __syncthreads();  // all waves done reading hbuf for step t

    // epilogue: row = 4*hi + r, col = 16*(4w+i) + lo
#pragma unroll
    for (int r = 0; r < 4; ++r)
#pragma unroll
      for (int i = 0; i < 4; ++i) {
        int row = hi * 4 + r;
        int col = w * 64 + i * 16 + lo;
        float s = acc[i][r] + xwv[r * 4 + i];
        float h = fast_tanh(s);
        out[((size_t)(g * 16 + row) * T_S + t) * DIM + col] = h;
        st_h(row, col, f2bf(h));
      }

    __syncthreads();  // h_t fully written before step t+1 reads
  }
}

// ---------------------------------------------------------------------------
extern "C" void kernel_launch(void* const* d_in, const int* in_sizes, int n_in,
                              void* d_out, int out_size, void* d_ws, size_t ws_size,
                              hipStream_t stream) {
  const float* x  = (const float*)d_in[0];
  const float* h0 = (const float*)d_in[1];
  const float* Wx = (const float*)d_in[2];
  const float* Wh = (const float*)d_in[3];
  const float* b  = (const float*)d_in[4];
  float* out = (float*)d_out;

  char* ws = (char*)d_ws;
  uint4* whb = (uint4*)ws;                  // 512 KB
  uint4* wxb = (uint4*)(ws + 524288);       // 512 KB

  prepack<<<1024, 64, 0, stream>>>(Wx, Wh, wxb, whb);
  gemm_xw<<<2048, 256, 0, stream>>>(x, wxb, b, out);
  rnn_scan<<<4, 512, 0, stream>>>(h0, whb, out);
}

// Round 4
// 2202.577 us; speedup vs baseline: 3.8425x; 1.4690x over previous
//
#include <hip/hip_runtime.h>

// N=64, T=512, D=H=512.
//   xw = x @ Wx + b   -> d_out (fp32), big MFMA GEMM
//   h_t = tanh(h_{t-1} @ Wh + xw_t) -> overwrites d_out in place
//
// rnn_scan v3 (round-3 lessons):
//  - Wh FULLY resident per CU: 12 kk in VGPR (192 regs/wave) + 4 kk in LDS
//    (128 KB). No per-step L2 streaming (v2's 5-stage stream stalled ~200cy/stage).
//  - h double-buffered in LDS (2 x 16 KB) -> ONE barrier per step.
//  - raw s_barrier + manual lgkmcnt(0) (+sched_barrier fences): global loads/
//    stores stay in flight across the barrier (no vmcnt(0) drain per step).
//  - xw for step t prefetched during step t-1 (16 regs, single buffer; loads
//    issued after epilogue consumes the previous values).
// LDS total = 131072 (wlds) + 2*16384 (h ping-pong) = 163840 B (exactly 160 KB).

typedef __attribute__((ext_vector_type(8))) short short8;
typedef __attribute__((ext_vector_type(4))) float f32x4;

#define DIM 512
#define T_S 512

union Frag { uint4 v; short8 s; unsigned short u[8]; };

static __device__ __forceinline__ unsigned short f2bf(float f) {
  union { float f; unsigned u; } v;
  v.f = f;
  unsigned r = v.u + 0x7FFFu + ((v.u >> 16) & 1u);
  return (unsigned short)(r >> 16);
}

static __device__ __forceinline__ float fast_tanh(float s) {
  float e = __builtin_amdgcn_exp2f(2.885390082f * s);
  return 1.0f - 2.0f * __builtin_amdgcn_rcpf(e + 1.0f);
}

// ---------------------------------------------------------------------------
// Pack W (512x512 fp32) into bf16 MFMA B-fragments.
// Frag (kk, cc): lane l holds B[k=32kk+8(l>>4)+j][col=16cc+(l&15)], j=0..7,
// at dst[(kk*32+cc)*64 + lane].
// ---------------------------------------------------------------------------
__global__ __launch_bounds__(64) void prepack(const float* __restrict__ Wx,
                                              const float* __restrict__ Wh,
                                              uint4* __restrict__ wxb,
                                              uint4* __restrict__ whb) {
  int bid = blockIdx.x;
  int mat = bid >> 9;
  int idx = bid & 511;
  int kk = idx >> 5, cc = idx & 31;
  int lane = threadIdx.x;
  int lo = lane & 15, hi = lane >> 4;
  const float* src = mat ? Wh : Wx;
  uint4* dst = mat ? whb : wxb;
  int col = cc * 16 + lo;
  int kbase = kk * 32 + hi * 8;
  Frag fr;
#pragma unroll
  for (int j = 0; j < 8; ++j)
    fr.u[j] = f2bf(src[(size_t)(kbase + j) * DIM + col]);
  dst[(kk * 32 + cc) * 64 + lane] = fr.v;
}

// ---------------------------------------------------------------------------
// xw = x @ Wx + b -> out (fp32). M=32768, K=N=512. Unchanged from round 2.
// ---------------------------------------------------------------------------
__global__ __launch_bounds__(256) void gemm_xw(const float* __restrict__ x,
                                               const uint4* __restrict__ wxb,
                                               const float* __restrict__ bias,
                                               float* __restrict__ out) {
  int bid = blockIdx.x;
  int m = bid >> 2, nb = bid & 3;
  int wave = threadIdx.x >> 6, lane = threadIdx.x & 63;
  int lo = lane & 15, hi = lane >> 4;
  int rowbase = m * 64;
  int colbase = nb * 128 + wave * 32;

  f32x4 acc[4][2];
#pragma unroll
  for (int mi = 0; mi < 4; ++mi)
#pragma unroll
    for (int ni = 0; ni < 2; ++ni) acc[mi][ni] = (f32x4){0.f, 0.f, 0.f, 0.f};

  for (int kk = 0; kk < 16; ++kk) {
    short8 afrag[4];
#pragma unroll
    for (int mi = 0; mi < 4; ++mi) {
      const float* ap = x + (size_t)(rowbase + mi * 16 + lo) * DIM + kk * 32 + hi * 8;
      float4 f0 = *(const float4*)ap;
      float4 f1 = *(const float4*)(ap + 4);
      Frag a;
      a.u[0] = f2bf(f0.x); a.u[1] = f2bf(f0.y); a.u[2] = f2bf(f0.z); a.u[3] = f2bf(f0.w);
      a.u[4] = f2bf(f1.x); a.u[5] = f2bf(f1.y); a.u[6] = f2bf(f1.z); a.u[7] = f2bf(f1.w);
      afrag[mi] = a.s;
    }
#pragma unroll
    for (int ni = 0; ni < 2; ++ni) {
      int cc = nb * 8 + wave * 2 + ni;
      Frag b;
      b.v = wxb[(kk * 32 + cc) * 64 + lane];
#pragma unroll
      for (int mi = 0; mi < 4; ++mi)
        acc[mi][ni] = __builtin_amdgcn_mfma_f32_16x16x32_bf16(afrag[mi], b.s, acc[mi][ni], 0, 0, 0);
    }
  }
#pragma unroll
  for (int ni = 0; ni < 2; ++ni) {
    int col = colbase + ni * 16 + lo;
    float bv = bias[col];
#pragma unroll
    for (int mi = 0; mi < 4; ++mi)
#pragma unroll
      for (int r = 0; r < 4; ++r) {
        int row = rowbase + mi * 16 + hi * 4 + r;
        out[(size_t)row * DIM + col] = acc[mi][ni][r] + bv;
      }
  }
}

// ---------------------------------------------------------------------------
// Recurrent scan v3. grid = 4 blocks x 512 thr (8 waves, 2/SIMD).
// Block g: batch rows [16g,16g+16), all 512 cols. Wave w: cols [64w,64w+64).
// ---------------------------------------------------------------------------
__shared__ uint4 wlds[4][32][64];          // 128 KB: Wh kk=12..15  [kk-12][cc][lane]
__shared__ unsigned short hA[16 * 512];    // 16 KB ping
__shared__ unsigned short hB[16 * 512];    // 16 KB pong

static __device__ __forceinline__ uint4 ld_h(const unsigned short* buf, int lo,
                                             int kk, int hi) {
  // A-frag: row=lo, k0 = kk*32 + hi*8 -> 16 B, XOR-swizzled by row
  int byte = lo * 1024 + ((kk * 64 + hi * 16) ^ ((lo & 7) << 4));
  return *(const uint4*)((const char*)buf + byte);
}

static __device__ __forceinline__ void st_h(unsigned short* buf, int row, int col,
                                            unsigned short v) {
  int byte = row * 1024 + ((col * 2) ^ ((row & 7) << 4));
  *(unsigned short*)((char*)buf + byte) = v;
}

static __device__ __forceinline__ void step_body(
    const unsigned short* RD, unsigned short* WR, int t, int g, int w, int lane,
    int lo, int hi, const uint4 (&bw)[12][4], float (&xwv)[16],
    float* __restrict__ out) {
  f32x4 acc[4];
#pragma unroll
  for (int i = 0; i < 4; ++i) acc[i] = (f32x4){0.f, 0.f, 0.f, 0.f};

  // kk 0..11: VGPR-resident weights
#pragma unroll
  for (int kk = 0; kk < 12; ++kk) {
    Frag a; a.v = ld_h(RD, lo, kk, hi);
#pragma unroll
    for (int i = 0; i < 4; ++i) {
      Frag b; b.v = bw[kk][i];
      acc[i] = __builtin_amdgcn_mfma_f32_16x16x32_bf16(a.s, b.s, acc[i], 0, 0, 0);
    }
  }
  // kk 12..15: LDS-resident weights (stride-1 uint4 reads, conflict-free)
#pragma unroll
  for (int kk = 12; kk < 16; ++kk) {
    Frag a; a.v = ld_h(RD, lo, kk, hi);
#pragma unroll
    for (int i = 0; i < 4; ++i) {
      Frag b; b.v = wlds[kk - 12][w * 4 + i][lane];
      acc[i] = __builtin_amdgcn_mfma_f32_16x16x32_bf16(a.s, b.s, acc[i], 0, 0, 0);
    }
  }

  // epilogue: row = 4*hi + r, col = 64w + 16i + lo
#pragma unroll
  for (int r = 0; r < 4; ++r) {
    float* orow = out + (((size_t)(g * 16 + hi * 4 + r) * T_S + t) * DIM) + w * 64 + lo;
#pragma unroll
    for (int i = 0; i < 4; ++i) {
      float sv = acc[i][r] + xwv[r * 4 + i];
      float h = fast_tanh(sv);
      orow[i * 16] = h;
      st_h(WR, hi * 4 + r, w * 64 + i * 16 + lo, f2bf(h));
    }
  }

  // prefetch xw for step t+1 (consumed next epilogue ~a full step later;
  // t=511 clamps to 511 -> values loaded but never used)
  int tn = (t < T_S - 1) ? (t + 1) : (T_S - 1);
#pragma unroll
  for (int r = 0; r < 4; ++r) {
    const float* lrow = out + (((size_t)(g * 16 + hi * 4 + r) * T_S + tn) * DIM) + w * 64 + lo;
#pragma unroll
    for (int i = 0; i < 4; ++i) xwv[r * 4 + i] = lrow[i * 16];
  }

  // one barrier per step: h writes visible, no vmem drain (raw s_barrier)
  asm volatile("s_waitcnt lgkmcnt(0)" ::: "memory");
  __builtin_amdgcn_sched_barrier(0);
  __builtin_amdgcn_s_barrier();
  __builtin_amdgcn_sched_barrier(0);
}

__global__ __launch_bounds__(512, 2) void rnn_scan(const float* __restrict__ h0,
                                                   const uint4* __restrict__ whb,
                                                   float* __restrict__ out) {
  int g = blockIdx.x;
  int w = threadIdx.x >> 6, lane = threadIdx.x & 63;
  int lo = lane & 15, hi = lane >> 4;

  // VGPR-resident Wh: kk 0..11 for this wave's 4 col-tiles (192 VGPRs)
  uint4 bw[12][4];
#pragma unroll
  for (int kk = 0; kk < 12; ++kk)
#pragma unroll
    for (int i = 0; i < 4; ++i)
      bw[kk][i] = whb[(kk * 32 + (w * 4 + i)) * 64 + lane];

  // LDS-resident Wh: kk 12..15, all 32 cc (coalesced cooperative stage)
#pragma unroll
  for (int e = 0; e < 16; ++e) {
    int idx = e * 512 + threadIdx.x;
    int s = idx >> 11, rem = idx & 2047;
    wlds[s][rem >> 6][rem & 63] = whb[((12 + s) * 32 + (rem >> 6)) * 64 + (rem & 63)];
  }

  // h_0 into ping buffer (bf16, swizzled)
#pragma unroll
  for (int r = 0; r < 4; ++r)
#pragma unroll
    for (int i = 0; i < 4; ++i) {
      int row = hi * 4 + r;
      int col = w * 64 + i * 16 + lo;
      st_h(hA, row, col, f2bf(h0[(size_t)(g * 16 + row) * DIM + col]));
    }

  // prime xw for t=0
  float xwv[16];
#pragma unroll
  for (int r = 0; r < 4; ++r)
#pragma unroll
    for (int i = 0; i < 4; ++i)
      xwv[r * 4 + i] =
          out[((size_t)(g * 16 + hi * 4 + r) * T_S + 0) * DIM + w * 64 + i * 16 + lo];

  __syncthreads();  // heavy barrier once before the loop

#pragma unroll 1
  for (int t = 0; t < T_S; t += 2) {
    step_body(hA, hB, t,     g, w, lane, lo, hi, bw, xwv, out);
    step_body(hB, hA, t + 1, g, w, lane, lo, hi, bw, xwv, out);
  }
}

// ---------------------------------------------------------------------------
extern "C" void kernel_launch(void* const* d_in, const int* in_sizes, int n_in,
                              void* d_out, int out_size, void* d_ws, size_t ws_size,
                              hipStream_t stream) {
  const float* x  = (const float*)d_in[0];
  const float* h0 = (const float*)d_in[1];
  const float* Wx = (const float*)d_in[2];
  const float* Wh = (const float*)d_in[3];
  const float* b  = (const float*)d_in[4];
  float* out = (float*)d_out;

  char* ws = (char*)d_ws;
  uint4* whb = (uint4*)ws;                  // 512 KB
  uint4* wxb = (uint4*)(ws + 524288);       // 512 KB

  prepack<<<1024, 64, 0, stream>>>(Wx, Wh, wxb, whb);
  gemm_xw<<<2048, 256, 0, stream>>>(x, wxb, b, out);
  rnn_scan<<<4, 512, 0, stream>>>(h0, whb, out);
}